// Round 19
// baseline (874.240 us; speedup 1.0000x reference)
//
#include <hip/hip_runtime.h>

#define DZ 64
#define DX 32
#define DS 16
#define TT 1024
#define NS 1024
#define SNZ (NS * DZ)
#define SNX (NS * DX)
#define SU4 (NS * DS / 4)     // per-step stride in float4 units (u)

// ---- LDS layout (floats) ----
// staging (read once into registers):
#define AW_B 0
#define C_B  (AW_B + DZ * (DZ + 1))
#define B_B  (C_B + DZ * (DS + 1))
#define SMEM_FLOATS (B_B + DX * (DZ + 1))   // 7328 floats = 29.3 KB
// runtime overlay ALIASES the AW staging region (anti-remat clobber):
#define ZR_O 0                 // raw z_t   [par2][64]
#define RZ_O 128               // relu z_t  [par2][64]

__device__ __forceinline__ float softplus_eps(float x) {
    // jax.nn.softplus = max(x,0) + log1p(exp(-|x|)); +1e-6
    return fmaxf(x, 0.f) + log1pf(expf(-fabsf(x))) + 1e-6f;
}

// LDS-only barrier (R16-proven): orders the z publish without draining
// in-flight global prefetch loads.
__device__ __forceinline__ void lds_barrier() {
    asm volatile("s_waitcnt lgkmcnt(0)" ::: "memory");
    __builtin_amdgcn_s_barrier();
}

// OUTPUT-split: wave w owns z' dims [32w,32w+32). Lane=(i=32w+(lane&31),
// h=lane>>5 k-half). The k-half partials merge via IN-WAVE shfl_xor(32)
// -> the cross-wave LDS partial exchange (2nd round-trip, ~200cyc) of the
// R12/R16 k-split is GONE. One publish + one barrier + one read per step.
// 1024 blocks x 128 thr = 2048 waves (proven 2/SIMD regime).
__global__ __launch_bounds__(128, 1) void plrnn_osplit_kernel(
    const float* __restrict__ u,   // (T, N, 16)
    const float* __restrict__ z0,  // (N, 64)
    const float* __restrict__ nz,  // (T, N, 64)
    const float* __restrict__ nx,  // (T, N, 32)
    const float* __restrict__ AW,  // (64, 64)
    const float* __restrict__ Cm,  // (64, 16)
    const float* __restrict__ Bm,  // (32, 64)
    const float* __restrict__ Q,   // (64,)
    const float* __restrict__ R,   // (32,)
    float* __restrict__ zo,        // (T, N, 64)
    float* __restrict__ xo)        // (T, N, 32)
{
    const int tid  = threadIdx.x;
    const int lane = tid & 63;
    const int wv   = tid >> 6;            // output-half owner: 0 or 1
    const int il   = lane & 31;
    const int i    = 32 * wv + il;        // owned z' dim
    const int h    = lane >> 5;           // k-half for the W-dot
    const int kbW  = 32 * h;
    const int p16  = lane & 15;
    const int kq   = lane >> 4;           // k-quarter for the x-dot (0..3)
    const int kbX  = 16 * kq;
    const int pp   = 16 * wv + p16;       // owned x row
    const int sim  = __builtin_amdgcn_readfirstlane((int)blockIdx.x);

    __shared__ float smem[SMEM_FLOATS];

    {   // one-time stage (128 threads): AW 32/thr, C 8/thr, B 16/thr
        const int r = tid >> 1;
        const int c = (tid & 1) * 32;
        #pragma unroll
        for (int k = 0; k < 32; ++k) smem[AW_B + r * (DZ + 1) + c + k] = AW[r * DZ + c + k];
        const int cc = (tid & 1) * 8;
        #pragma unroll
        for (int k = 0; k < 8; ++k) smem[C_B + r * (DS + 1) + cc + k] = Cm[r * DS + cc + k];
        const int br = tid >> 2;
        const int bc = (tid & 3) * 16;
        #pragma unroll
        for (int k = 0; k < 16; ++k) smem[B_B + br * (DZ + 1) + bc + k] = Bm[br * DZ + bc + k];
    }
    __syncthreads();

    // per-lane weights -> registers (compile-time indices; proven pattern)
    float Wrow[32];                       // W_off[i][kbW .. kbW+31]
    #pragma unroll
    for (int j = 0; j < 32; ++j) {
        const int k = kbW + j;
        const float w = smem[AW_B + i * (DZ + 1) + k];
        Wrow[j] = (k == i) ? 0.f : w;     // zero diagonal
    }
    const float Ad = smem[AW_B + i * (DZ + 1) + i];
    float Crow[16];                       // FULL C row for dim i
    #pragma unroll
    for (int j = 0; j < 16; ++j) Crow[j] = smem[C_B + i * (DS + 1) + j];
    float Brow[16];                       // B[pp][kbX .. kbX+15]
    #pragma unroll
    for (int j = 0; j < 16; ++j) Brow[j] = smem[B_B + pp * (DZ + 1) + kbX + j];

    const float qv = softplus_eps(Q[i]);
    const float rv = softplus_eps(R[pp]);

    __syncthreads();   // staging reads done before overlay clobbers AW region

    float zl = z0[sim * DZ + i];          // both h-copies identical

    const float* pnz = nz + sim * DZ + i;     // dup across h: same lines
    const float* pnx = nx + sim * DX + pp;    // dup across kq: same lines
    const float4* pu = (const float4*)(u + sim * DS);   // wave-uniform
    float* zob = zo + sim * DZ + i;
    float* xob = xo + sim * DX + pp;

    // prefetch: nz/nx depth 4, u depth 2 (alternating buffers)
    float nzp[4], nxp[4];
    #pragma unroll
    for (int j = 0; j < 4; ++j) {
        nzp[j] = pnz[j * SNZ];
        nxp[j] = pnx[j * SNX];
    }
    float4 ub[2][4];
    #pragma unroll
    for (int j = 0; j < 2; ++j)
        #pragma unroll
        for (int q = 0; q < 4; ++q) ub[j][q] = pu[j * SU4 + q];

    for (int t0 = 0; t0 < TT; t0 += 4) {
        #pragma unroll
        for (int j = 0; j < 4; ++j) {
            const int t   = t0 + j;
            const int par = j & 1;
            const float vnz = nzp[j];
            const float vnx = nxp[j];

            // ---- publish z_t: each lane writes ONE word (h0 raw, h1 relu)
            if (h == 0) smem[ZR_O + par * 64 + i] = zl;
            else        smem[RZ_O + par * 64 + i] = fmaxf(zl, 0.f);
            if (lane < 32) zob[t * SNZ] = zl;     // emit z_t (pre-update)

            // C-dot: full 16-k per lane, register/SGPR operands (fills shadow)
            float cd0, cd1, cd2, cd3;
            {
                const float4 u0 = ub[j & 1][0], u1 = ub[j & 1][1];
                const float4 u2 = ub[j & 1][2], u3 = ub[j & 1][3];
                cd0 = Crow[ 0] * u0.x;            cd1 = Crow[ 1] * u0.y;
                cd2 = Crow[ 2] * u0.z;            cd3 = Crow[ 3] * u0.w;
                cd0 = fmaf(Crow[ 4], u1.x, cd0);  cd1 = fmaf(Crow[ 5], u1.y, cd1);
                cd2 = fmaf(Crow[ 6], u1.z, cd2);  cd3 = fmaf(Crow[ 7], u1.w, cd3);
                cd0 = fmaf(Crow[ 8], u2.x, cd0);  cd1 = fmaf(Crow[ 9], u2.y, cd1);
                cd2 = fmaf(Crow[10], u2.z, cd2);  cd3 = fmaf(Crow[11], u2.w, cd3);
                cd0 = fmaf(Crow[12], u3.x, cd0);  cd1 = fmaf(Crow[13], u3.y, cd1);
                cd2 = fmaf(Crow[14], u3.z, cd2);  cd3 = fmaf(Crow[15], u3.w, cd3);
            }
            const float cds = (cd0 + cd1) + (cd2 + cd3);

            // refill prefetch (clamped; tail values loaded but unused)
            {
                int tn = t + 4; tn = (tn < TT) ? tn : (TT - 1);
                nzp[j] = pnz[tn * SNZ];
                nxp[j] = pnx[tn * SNX];
                int tu = t + 2; tu = (tu < TT) ? tu : (TT - 1);
                #pragma unroll
                for (int q = 0; q < 4; ++q) ub[j & 1][q] = pu[tu * SU4 + q];
            }

            lds_barrier();   // partner's publish visible; vmem stays in flight

            // W-half dot: 8 broadcast ds_read_b128 of relu(z_t)
            float m0, m1, m2, m3;
            {
                const float* rz = &smem[RZ_O + par * 64 + kbW];
                const float4 z0v = *(const float4*)(rz + 0);
                const float4 z1v = *(const float4*)(rz + 4);
                const float4 z2v = *(const float4*)(rz + 8);
                const float4 z3v = *(const float4*)(rz + 12);
                const float4 z4v = *(const float4*)(rz + 16);
                const float4 z5v = *(const float4*)(rz + 20);
                const float4 z6v = *(const float4*)(rz + 24);
                const float4 z7v = *(const float4*)(rz + 28);
                m0 = Wrow[ 0] * z0v.x;           m1 = Wrow[ 1] * z0v.y;
                m2 = Wrow[ 2] * z0v.z;           m3 = Wrow[ 3] * z0v.w;
                m0 = fmaf(Wrow[ 4], z1v.x, m0);  m1 = fmaf(Wrow[ 5], z1v.y, m1);
                m2 = fmaf(Wrow[ 6], z1v.z, m2);  m3 = fmaf(Wrow[ 7], z1v.w, m3);
                m0 = fmaf(Wrow[ 8], z2v.x, m0);  m1 = fmaf(Wrow[ 9], z2v.y, m1);
                m2 = fmaf(Wrow[10], z2v.z, m2);  m3 = fmaf(Wrow[11], z2v.w, m3);
                m0 = fmaf(Wrow[12], z3v.x, m0);  m1 = fmaf(Wrow[13], z3v.y, m1);
                m2 = fmaf(Wrow[14], z3v.z, m2);  m3 = fmaf(Wrow[15], z3v.w, m3);
                m0 = fmaf(Wrow[16], z4v.x, m0);  m1 = fmaf(Wrow[17], z4v.y, m1);
                m2 = fmaf(Wrow[18], z4v.z, m2);  m3 = fmaf(Wrow[19], z4v.w, m3);
                m0 = fmaf(Wrow[20], z5v.x, m0);  m1 = fmaf(Wrow[21], z5v.y, m1);
                m2 = fmaf(Wrow[22], z5v.z, m2);  m3 = fmaf(Wrow[23], z5v.w, m3);
                m0 = fmaf(Wrow[24], z6v.x, m0);  m1 = fmaf(Wrow[25], z6v.y, m1);
                m2 = fmaf(Wrow[26], z6v.z, m2);  m3 = fmaf(Wrow[27], z6v.w, m3);
                m0 = fmaf(Wrow[28], z7v.x, m0);  m1 = fmaf(Wrow[29], z7v.y, m1);
                m2 = fmaf(Wrow[30], z7v.z, m2);  m3 = fmaf(Wrow[31], z7v.w, m3);
            }
            float wsum = (m0 + m1) + (m2 + m3);
            wsum += __shfl_xor(wsum, 32);     // merge k-halves IN-WAVE

            // x-dot: 16-k quarter of raw z_t, merged by two shfls
            float xa0, xa1;
            {
                const float* zr = &smem[ZR_O + par * 64 + kbX];
                const float4 za = *(const float4*)(zr + 0);
                const float4 zb = *(const float4*)(zr + 4);
                const float4 zc = *(const float4*)(zr + 8);
                const float4 zd = *(const float4*)(zr + 12);
                xa0 = Brow[ 0] * za.x;           xa1 = Brow[ 1] * za.y;
                xa0 = fmaf(Brow[ 2], za.z, xa0); xa1 = fmaf(Brow[ 3], za.w, xa1);
                xa0 = fmaf(Brow[ 4], zb.x, xa0); xa1 = fmaf(Brow[ 5], zb.y, xa1);
                xa0 = fmaf(Brow[ 6], zb.z, xa0); xa1 = fmaf(Brow[ 7], zb.w, xa1);
                xa0 = fmaf(Brow[ 8], zc.x, xa0); xa1 = fmaf(Brow[ 9], zc.y, xa1);
                xa0 = fmaf(Brow[10], zc.z, xa0); xa1 = fmaf(Brow[11], zc.w, xa1);
                xa0 = fmaf(Brow[12], zd.x, xa0); xa1 = fmaf(Brow[13], zd.y, xa1);
                xa0 = fmaf(Brow[14], zd.z, xa0); xa1 = fmaf(Brow[15], zd.w, xa1);
            }
            float xp = xa0 + xa1;
            xp += __shfl_xor(xp, 16);         // merge kq pairs
            xp += __shfl_xor(xp, 32);         // merge kq quads
            if (lane < 16) xob[t * SNX] = fmaf(vnx, rv, xp);

            // z_{t+1} = A_diag*z + W-dot + C-dot + q*nz
            // (identical on both h-copies: all inputs bit-identical)
            zl = fmaf(qv, vnz, fmaf(Ad, zl, wsum + cds));
        }
    }
}

extern "C" void kernel_launch(void* const* d_in, const int* in_sizes, int n_in,
                              void* d_out, int out_size, void* d_ws, size_t ws_size,
                              hipStream_t stream) {
    const float* u_  = (const float*)d_in[0];
    const float* z0_ = (const float*)d_in[1];
    const float* nz_ = (const float*)d_in[2];
    const float* nx_ = (const float*)d_in[3];
    const float* AW_ = (const float*)d_in[4];
    const float* C_  = (const float*)d_in[5];
    const float* B_  = (const float*)d_in[6];
    const float* Q_  = (const float*)d_in[7];
    const float* R_  = (const float*)d_in[8];

    float* zo = (float*)d_out;                 // (T,N,64) first
    float* xo = zo + (size_t)TT * NS * DZ;     // then (T,N,32)

    hipLaunchKernelGGL(plrnn_osplit_kernel, dim3(NS), dim3(128), 0, stream,
                       u_, z0_, nz_, nx_, AW_, C_, B_, Q_, R_, zo, xo);
}